// Round 2
// baseline (4459.265 us; speedup 1.0000x reference)
//
#include <hip/hip_runtime.h>
#include <hip/hip_cooperative_groups.h>

namespace cg = cooperative_groups;

#define DI __device__ __forceinline__

DI float sigm(float x)  { return 1.0f / (1.0f + __expf(-x)); }
DI float tanh_(float x) { return 2.0f / (1.0f + __expf(-2.0f * x)) - 1.0f; }

DI void fma4(float4& a, float s, const float4& w) {
  a.x += s * w.x; a.y += s * w.y; a.z += s * w.z; a.w += s * w.w;
}
DI float4 relu4(float4 a) {
  return make_float4(fmaxf(a.x, 0.f), fmaxf(a.y, 0.f), fmaxf(a.z, 0.f), fmaxf(a.w, 0.f));
}

// ---------------- conv1: [1024,64,64,3] -> [1024,31,31,32], k4 s2 VALID, relu ----
// thread: (n, y, x-pair, c-quad). 2 x-positions x 4 channels per thread.
__global__ void conv1_k4(const float* __restrict__ in, const float* __restrict__ w,
                         const float* __restrict__ bias, float* __restrict__ out) {
  int idx = blockIdx.x * 256 + threadIdx.x;
  if (idx >= 1024 * 31 * 16 * 8) return;
  int c4 = idx & 7;  int t = idx >> 3;
  int xp = t & 15;   t >>= 4;
  int y = t % 31;    int n = t / 31;
  const float* ip = in + (((size_t)n * 64 + 2 * y) * 64 + 4 * xp) * 3;
  bool v1 = (xp < 15);                 // x1 = 2*xp+1 must be <= 30
  int off1 = v1 ? 6 : 0;               // clamp OOB reads (result discarded)
  float4 bv = *(const float4*)(bias + c4 * 4);
  float4 a0 = bv, a1 = bv;
#pragma unroll
  for (int ky = 0; ky < 4; ++ky) {
#pragma unroll
    for (int kx = 0; kx < 4; ++kx) {
      const float* ipr = ip + (ky * 64 + kx) * 3;
      const float* wp  = w + ((ky * 4 + kx) * 3) * 32 + c4 * 4;
#pragma unroll
      for (int ci = 0; ci < 3; ++ci) {
        float4 wv = *(const float4*)(wp + ci * 32);
        float i0 = ipr[ci], i1 = ipr[off1 + ci];
        fma4(a0, i0, wv);
        fma4(a1, i1, wv);
      }
    }
  }
  int x0 = 2 * xp;
  float* op = out + ((size_t)n * 31 * 31 + (size_t)y * 31 + x0) * 32 + c4 * 4;
  *(float4*)op = relu4(a0);
  if (v1) *(float4*)(op + 32) = relu4(a1);
}

// ---- generic k4 s2 VALID conv, 2 x-positions x 4 channels per thread, float4 loads ----
template <int CIN, int COUT, int WIN, int WOUT>
__global__ void conv_blk4(const float* __restrict__ in, const float* __restrict__ w,
                          const float* __restrict__ bias, float* __restrict__ out,
                          int img_stride) {
  constexpr int CH4 = COUT / 4;
  constexpr int XP  = WOUT / 2;
  int idx = blockIdx.x * 256 + threadIdx.x;
  if (idx >= 1024 * WOUT * XP * CH4) return;
  int c4 = idx % CH4; int t = idx / CH4;
  int xp = t % XP;    t /= XP;
  int y = t % WOUT;   int n = t / WOUT;
  const float* ip = in + (((size_t)n * WIN + 2 * y) * WIN + 4 * xp) * CIN;
  float4 bv = *(const float4*)(bias + c4 * 4);
  float4 a0 = bv, a1 = bv;
#pragma unroll
  for (int ky = 0; ky < 4; ++ky) {
#pragma unroll
    for (int kx = 0; kx < 4; ++kx) {
      const float* ipr = ip + (ky * WIN + kx) * CIN;
      const float* wp  = w + ((ky * 4 + kx) * CIN) * COUT + c4 * 4;
#pragma unroll 4
      for (int ci4 = 0; ci4 < CIN / 4; ++ci4) {
        float4 i0 = *(const float4*)(ipr + ci4 * 4);
        float4 i1 = *(const float4*)(ipr + 2 * CIN + ci4 * 4);
        const float* wq = wp + (size_t)(ci4 * 4) * COUT;
        float4 w0 = *(const float4*)(wq);
        fma4(a0, i0.x, w0); fma4(a1, i1.x, w0);
        float4 w1 = *(const float4*)(wq + COUT);
        fma4(a0, i0.y, w1); fma4(a1, i1.y, w1);
        float4 w2 = *(const float4*)(wq + 2 * COUT);
        fma4(a0, i0.z, w2); fma4(a1, i1.z, w2);
        float4 w3 = *(const float4*)(wq + 3 * COUT);
        fma4(a0, i0.w, w3); fma4(a1, i1.w, w3);
      }
    }
  }
  int x0 = 2 * xp;
  float* op = out + (size_t)n * img_stride + ((size_t)y * WOUT + x0) * COUT + c4 * 4;
  *(float4*)op          = relu4(a0);
  *(float4*)(op + COUT) = relu4(a1);
}

// ---- copy actions into xin columns 1024..1025 (row length 1026) ----
__global__ void act_copy(const float* __restrict__ act, float* __restrict__ xin) {
  int i = blockIdx.x * 256 + threadIdx.x;
  if (i < 2048) xin[(size_t)(i >> 1) * 1026 + 1024 + (i & 1)] = act[i];
}

// ---- xpart[t][b][2048] = xin[b*64+t][0..1026) @ k_l1[0..1026) + b_l1 ----
__global__ void gemm_xpart(const float* __restrict__ A, const float* __restrict__ Bw,
                           const float* __restrict__ bias, float* __restrict__ C) {
  __shared__ float As[16][64];
  __shared__ float Bs[16][64];
  const int tid = threadIdx.x;
  const int tx = tid & 15, ty = tid >> 4;
  const int m0 = blockIdx.y * 64, n0 = blockIdx.x * 64;
  float acc[4][4] = {};
  for (int k0 = 0; k0 < 1026; k0 += 16) {
#pragma unroll
    for (int i = 0; i < 4; ++i) {
      int lin = tid + i * 256;
      int ka = lin & 15, mm = lin >> 4;
      As[ka][mm] = (k0 + ka < 1026) ? A[(size_t)(m0 + mm) * 1026 + k0 + ka] : 0.0f;
      int kb = lin >> 6, nn = lin & 63;
      Bs[kb][nn] = (k0 + kb < 1026) ? Bw[(size_t)(k0 + kb) * 2048 + n0 + nn] : 0.0f;
    }
    __syncthreads();
#pragma unroll
    for (int kk = 0; kk < 16; ++kk) {
      float av[4], bv[4];
#pragma unroll
      for (int i = 0; i < 4; ++i) { av[i] = As[kk][ty * 4 + i]; bv[i] = Bs[kk][tx * 4 + i]; }
#pragma unroll
      for (int i = 0; i < 4; ++i)
#pragma unroll
        for (int j = 0; j < 4; ++j) acc[i][j] += av[i] * bv[j];
    }
    __syncthreads();
  }
#pragma unroll
  for (int i = 0; i < 4; ++i) {
    int m = m0 + ty * 4 + i;
    int xrow = (m & 63) * 16 + (m >> 6);   // (t, b)
#pragma unroll
    for (int j = 0; j < 4; ++j) {
      int n = n0 + tx * 4 + j;
      C[(size_t)xrow * 2048 + n] = acc[i][j] + bias[n];
    }
  }
}

// ---- persistent 2-layer LSTM, weights held in VGPRs across all 64 steps ----
// grid: 256 blocks x 256 thr (1 block/CU). Virtual col v = u*4 + gate so all 4
// gates of a u live in one block. L1: block owns u = {2*blk, 2*blk+1} (8 v-cols);
// thread (cidx1 = tid>>6 of 4 -> 2 v-cols, ks1 = tid&63, k = ks1+64i, i<8).
// L2: block owns u = blk (4 v-cols = 4 gates); thread (cidx2 = tid>>7 of 2 ->
// 2 gates, ks2 = tid&127, k = ks2+128i, i<6).
// h staged in LDS [k][b] stride 17 (conflict-free b32). Partials pre-reduced
// in-wave via shfl_xor (x4) before LDS reduction. One grid.sync per step.
__global__ void __launch_bounds__(256, 1)
lstm_k(const float* __restrict__ xpart,   // [64][16][2048] physical cols (incl b_l1)
       const float* __restrict__ kl1,     // [1538][2048]
       const float* __restrict__ kl2,     // [768][1024]
       const float* __restrict__ bl2,     // [1024]
       float* __restrict__ h1b,           // [2][512][16]
       float* __restrict__ c1,            // [512][16]
       float* __restrict__ h2b,           // [2][256][16]
       float* __restrict__ c2,            // [256][16]
       float* __restrict__ out_seq) {     // [16][64][256]
  cg::grid_group grid = cg::this_grid();
  __shared__ float stg[13056];   // 768*17
  __shared__ float red[2176];
  __shared__ float gsum[160];
  const int tid = threadIdx.x;
  const int blk = blockIdx.x;
  const float* Wh1 = kl1 + (size_t)1026 * 2048;

  const int cidx1 = tid >> 6, ks1 = tid & 63;
  const int cidx2 = tid >> 7, ks2 = tid & 127;

  // ---- preload weight slices into registers (one-time scattered loads) ----
  float w1r[2][8], w2r[2][6];
#pragma unroll
  for (int cc = 0; cc < 2; ++cc) {
    int vL = cidx1 * 2 + cc;
    int p  = (vL & 3) * 512 + blk * 2 + (vL >> 2);
#pragma unroll
    for (int i = 0; i < 8; ++i)
      w1r[cc][i] = Wh1[(size_t)(ks1 + (i << 6)) * 2048 + p];
  }
#pragma unroll
  for (int cc = 0; cc < 2; ++cc) {
    int p = (cidx2 * 2 + cc) * 256 + blk;
#pragma unroll
    for (int i = 0; i < 6; ++i)
      w2r[cc][i] = kl2[(size_t)(ks2 + (i << 7)) * 1024 + p];
  }

  for (int t = 0; t < 64; ++t) {
    const float* h1c = h1b + (size_t)(t & 1) * 8192;
    float* h1n       = h1b + (size_t)((t + 1) & 1) * 8192;
    const float* h2c = h2b + (size_t)(t & 1) * 4096;
    float* h2n       = h2b + (size_t)((t + 1) & 1) * 4096;

    __syncthreads();                       // stg reuse guard vs prev-iter L2 reads
    // ---- stage L1 h(t-1): h1c [512][16] -> stg[k*17 + b]
#pragma unroll
    for (int j = 0; j < 8; ++j) {
      int e0 = (tid + (j << 8)) << 2;
      float4 v = *(const float4*)(h1c + e0);
      int a = (e0 >> 4) * 17 + (e0 & 15);
      stg[a] = v.x; stg[a + 1] = v.y; stg[a + 2] = v.z; stg[a + 3] = v.w;
    }
    __syncthreads();

    float accA[16], accB[16];
#pragma unroll
    for (int b = 0; b < 16; ++b) { accA[b] = 0.f; accB[b] = 0.f; }
#pragma unroll
    for (int i = 0; i < 8; ++i) {
      const float* hp = stg + (ks1 + (i << 6)) * 17;
      float wa = w1r[0][i], wb = w1r[1][i];
#pragma unroll
      for (int b = 0; b < 16; ++b) {
        float h = hp[b];
        accA[b] = fmaf(wa, h, accA[b]);
        accB[b] = fmaf(wb, h, accB[b]);
      }
    }
    // in-wave pre-reduction: xor1 splits cols, xor2 splits b-halves
    float v16[16];
#pragma unroll
    for (int b = 0; b < 16; ++b) {
      float tA = __shfl_xor(accA[b], 1);
      float tB = __shfl_xor(accB[b], 1);
      v16[b] = (ks1 & 1) ? (accB[b] + tB) : (accA[b] + tA);
    }
    float v8[8];
#pragma unroll
    for (int j = 0; j < 8; ++j) {
      float t0 = __shfl_xor(v16[j], 2);
      float t8 = __shfl_xor(v16[j + 8], 2);
      v8[j] = (ks1 & 2) ? (v16[j + 8] + t8) : (v16[j] + t0);
    }
    {
      int colL = cidx1 * 2 + (ks1 & 1);
      int bh = (ks1 >> 1) & 1;
      int ksG = ks1 >> 2;                  // 0..15
#pragma unroll
      for (int j = 0; j < 8; ++j)
        red[(colL * 16 + bh * 8 + j) * 17 + ksG] = v8[j];
    }
    __syncthreads();
    if (tid < 128) {                       // gate sums: (vL = tid>>4, b = tid&15)
      float s = 0.f;
#pragma unroll
      for (int k = 0; k < 16; ++k) s += red[tid * 17 + k];
      int vL = tid >> 4, b = tid & 15;
      int p = (vL & 3) * 512 + blk * 2 + (vL >> 2);
      s += xpart[(size_t)((t << 4) + b) * 2048 + p];
      gsum[vL * 17 + b] = s;
    }
    __syncthreads();
    if (tid < 32) {                        // cell update: (uL = tid>>4, b = tid&15)
      int uL = tid >> 4, b = tid & 15;
      int u = blk * 2 + uL;
      float gi = gsum[(uL * 4 + 0) * 17 + b];
      float gj = gsum[(uL * 4 + 1) * 17 + b];
      float gf = gsum[(uL * 4 + 2) * 17 + b];
      float go = gsum[(uL * 4 + 3) * 17 + b];
      float cold = c1[u * 16 + b];
      float cn = sigm(gf + 1.0f) * cold + sigm(gi) * tanh_(gj);
      float hn = sigm(go) * tanh_(cn);
      c1[u * 16 + b] = cn;
      h1n[u * 16 + b] = hn;
    }
    grid.sync();                           // publish h1n (and order h2n/stg across steps)

    // ---- stage L2 input: h1n [512][16] ++ h2c [256][16] -> stg[k*17 + b]
#pragma unroll
    for (int j = 0; j < 12; ++j) {
      int e0 = (tid + (j << 8)) << 2;
      float4 v = (e0 < 8192) ? *(const float4*)(h1n + e0)
                             : *(const float4*)(h2c + (e0 - 8192));
      int a = (e0 >> 4) * 17 + (e0 & 15);
      stg[a] = v.x; stg[a + 1] = v.y; stg[a + 2] = v.z; stg[a + 3] = v.w;
    }
    __syncthreads();
#pragma unroll
    for (int b = 0; b < 16; ++b) { accA[b] = 0.f; accB[b] = 0.f; }
#pragma unroll
    for (int i = 0; i < 6; ++i) {
      const float* hp = stg + (ks2 + (i << 7)) * 17;
      float wa = w2r[0][i], wb = w2r[1][i];
#pragma unroll
      for (int b = 0; b < 16; ++b) {
        float h = hp[b];
        accA[b] = fmaf(wa, h, accA[b]);
        accB[b] = fmaf(wb, h, accB[b]);
      }
    }
#pragma unroll
    for (int b = 0; b < 16; ++b) {
      float tA = __shfl_xor(accA[b], 1);
      float tB = __shfl_xor(accB[b], 1);
      v16[b] = (ks2 & 1) ? (accB[b] + tB) : (accA[b] + tA);
    }
#pragma unroll
    for (int j = 0; j < 8; ++j) {
      float t0 = __shfl_xor(v16[j], 2);
      float t8 = __shfl_xor(v16[j + 8], 2);
      v8[j] = (ks2 & 2) ? (v16[j + 8] + t8) : (v16[j] + t0);
    }
    {
      int gL = cidx2 * 2 + (ks2 & 1);
      int bh = (ks2 >> 1) & 1;
      int ksG = ks2 >> 2;                  // 0..31
#pragma unroll
      for (int j = 0; j < 8; ++j)
        red[(gL * 16 + bh * 8 + j) * 33 + ksG] = v8[j];
    }
    __syncthreads();
    if (tid < 64) {                        // gate sums: (gL = tid>>4, b = tid&15)
      float s = 0.f;
#pragma unroll
      for (int k = 0; k < 32; ++k) s += red[tid * 33 + k];
      int gL = tid >> 4, b = tid & 15;
      s += bl2[gL * 256 + blk];
      gsum[gL * 17 + b] = s;
    }
    __syncthreads();
    if (tid < 16) {                        // cell update, u = blk
      int b = tid, u = blk;
      float gi = gsum[0 * 17 + b];
      float gj = gsum[1 * 17 + b];
      float gf = gsum[2 * 17 + b];
      float go = gsum[3 * 17 + b];
      float cold = c2[u * 16 + b];
      float cn = sigm(gf + 1.0f) * cold + sigm(gi) * tanh_(gj);
      float hn = sigm(go) * tanh_(cn);
      c2[u * 16 + b] = cn;
      h2n[u * 16 + b] = hn;
      out_seq[(size_t)((b << 6) + t) * 256 + u] = hn;
    }
    // loop-top __syncthreads orders stg reuse; next grid.sync orders h2n.
  }
}

// ---- dense head: relu(lstm_out @ wd1 + bd1) @ wd2 + bd2 -> [1024] ----
__global__ void head_k(const float* __restrict__ xin, const float* __restrict__ wd1,
                       const float* __restrict__ bd1, const float* __restrict__ wd2,
                       const float* __restrict__ bd2, float* __restrict__ out) {
  __shared__ float xs[4][256];
  __shared__ float ps[4][128];
  int r0 = blockIdx.x * 4;
  int tid = threadIdx.x;
  for (int i = tid; i < 1024; i += 128) xs[i >> 8][i & 255] = xin[(size_t)r0 * 256 + i];
  __syncthreads();
  float w2 = wd2[tid];
  float bb = bd1[tid];
#pragma unroll
  for (int rr = 0; rr < 4; ++rr) {
    float acc = bb;
#pragma unroll 8
    for (int k = 0; k < 256; ++k) acc += xs[rr][k] * wd1[k * 128 + tid];
    ps[rr][tid] = fmaxf(acc, 0.0f) * w2;
  }
  __syncthreads();
  if (tid < 4) {
    float s = bd2[0];
    for (int k = 0; k < 128; ++k) s += ps[tid][k];
    out[r0 + tid] = s;
  }
}

extern "C" void kernel_launch(void* const* d_in, const int* in_sizes, int n_in,
                              void* d_out, int out_size, void* d_ws, size_t ws_size,
                              hipStream_t stream) {
  const float* frames  = (const float*)d_in[0];
  const float* actions = (const float*)d_in[1];
  const float* w1 = (const float*)d_in[2];   const float* b1 = (const float*)d_in[3];
  const float* w2 = (const float*)d_in[4];   const float* b2 = (const float*)d_in[5];
  const float* w3 = (const float*)d_in[6];   const float* b3 = (const float*)d_in[7];
  const float* w4 = (const float*)d_in[8];   const float* b4 = (const float*)d_in[9];
  const float* kl1 = (const float*)d_in[10]; const float* bl1 = (const float*)d_in[11];
  const float* kl2 = (const float*)d_in[12]; const float* bl2 = (const float*)d_in[13];
  const float* wd1 = (const float*)d_in[14]; const float* bd1 = (const float*)d_in[15];
  const float* wd2 = (const float*)d_in[16]; const float* bd2 = (const float*)d_in[17];
  float* out = (float*)d_out;

  float* ws = (float*)d_ws;
  // overlayed layout (floats): a1[31.49M] | a2[12.85M] ; a3 overlays a1, xin overlays a2
  float* a1    = ws;                 // [1024][31][31][32]
  float* a2    = ws + 31490048u;     // [1024][14][14][64]
  float* a3    = ws;                 // [1024][6][6][128]   (a1 dead)
  float* xin   = ws + 31490048u;     // [1024][1026]        (a2 dead)
  float* xpart = ws + 44335104u;     // [64][16][2048]
  float* h1b   = ws + 46432256u;     // [2][512][16]
  float* c1    = ws + 46448640u;     // [512][16]
  float* h2b   = ws + 46456832u;     // [2][256][16]
  float* c2    = ws + 46465024u;     // [256][16]
  float* lout  = ws + 46469120u;     // [16][64][256]

  hipMemsetAsync(h1b, 0, (16384 + 8192 + 8192 + 4096) * sizeof(float), stream);

  conv1_k4<<<15872, 256, 0, stream>>>(frames, w1, b1, a1);
  conv_blk4<32, 64, 31, 14><<<6272, 256, 0, stream>>>(a1, w2, b2, a2, 14 * 14 * 64);
  conv_blk4<64, 128, 14, 6><<<2304, 256, 0, stream>>>(a2, w3, b3, a3, 6 * 6 * 128);
  conv_blk4<128, 256, 6, 2><<<512, 256, 0, stream>>>(a3, w4, b4, xin, 1026);
  act_copy<<<8, 256, 0, stream>>>(actions, xin);
  gemm_xpart<<<dim3(32, 16), 256, 0, stream>>>(xin, kl1, bl1, xpart);

  void* args[9];
  args[0] = (void*)&xpart; args[1] = (void*)&kl1; args[2] = (void*)&kl2; args[3] = (void*)&bl2;
  args[4] = (void*)&h1b;   args[5] = (void*)&c1;  args[6] = (void*)&h2b; args[7] = (void*)&c2;
  args[8] = (void*)&lout;
  hipLaunchCooperativeKernel((void*)lstm_k, dim3(256), dim3(256), args, 0, stream);

  head_k<<<256, 128, 0, stream>>>(lout, wd1, bd1, wd2, bd2, out);
}

// Round 3
// 3492.620 us; speedup vs baseline: 1.2768x; 1.2768x over previous
//
#include <hip/hip_runtime.h>

#define DI __device__ __forceinline__

DI float sigm(float x)  { return 1.0f / (1.0f + __expf(-x)); }
DI float tanh_(float x) { return 2.0f / (1.0f + __expf(-2.0f * x)) - 1.0f; }

DI void fma4(float4& a, float s, const float4& w) {
  a.x += s * w.x; a.y += s * w.y; a.z += s * w.z; a.w += s * w.w;
}
DI float4 relu4(float4 a) {
  return make_float4(fmaxf(a.x, 0.f), fmaxf(a.y, 0.f), fmaxf(a.z, 0.f), fmaxf(a.w, 0.f));
}

// ---------------- conv1: [1024,64,64,3] -> [1024,31,31,32], k4 s2 VALID, relu ----
__global__ void conv1_k4(const float* __restrict__ in, const float* __restrict__ w,
                         const float* __restrict__ bias, float* __restrict__ out) {
  int idx = blockIdx.x * 256 + threadIdx.x;
  if (idx >= 1024 * 31 * 16 * 8) return;
  int c4 = idx & 7;  int t = idx >> 3;
  int xp = t & 15;   t >>= 4;
  int y = t % 31;    int n = t / 31;
  const float* ip = in + (((size_t)n * 64 + 2 * y) * 64 + 4 * xp) * 3;
  bool v1 = (xp < 15);
  int off1 = v1 ? 6 : 0;
  float4 bv = *(const float4*)(bias + c4 * 4);
  float4 a0 = bv, a1 = bv;
#pragma unroll
  for (int ky = 0; ky < 4; ++ky) {
#pragma unroll
    for (int kx = 0; kx < 4; ++kx) {
      const float* ipr = ip + (ky * 64 + kx) * 3;
      const float* wp  = w + ((ky * 4 + kx) * 3) * 32 + c4 * 4;
#pragma unroll
      for (int ci = 0; ci < 3; ++ci) {
        float4 wv = *(const float4*)(wp + ci * 32);
        float i0 = ipr[ci], i1 = ipr[off1 + ci];
        fma4(a0, i0, wv);
        fma4(a1, i1, wv);
      }
    }
  }
  int x0 = 2 * xp;
  float* op = out + ((size_t)n * 31 * 31 + (size_t)y * 31 + x0) * 32 + c4 * 4;
  *(float4*)op = relu4(a0);
  if (v1) *(float4*)(op + 32) = relu4(a1);
}

// ---- k4 s2 VALID conv with weight slice staged in 64 KB LDS ----
// 512 thr. thread = (xpu-local, col-quad). 2 x-positions x 4 cols per thread.
// grid = (xpu_total/XPB, COUT/NTILE). K*NTILE*4 = 65536 bytes.
template <int CIN, int COUT, int NTILE, int WIN, int WOUT>
__global__ __launch_bounds__(512)
void conv_lds(const float* __restrict__ in, const float* __restrict__ w,
              const float* __restrict__ bias, float* __restrict__ out, int ostride) {
  constexpr int K    = 16 * CIN;
  constexpr int NC4  = NTILE / 4;
  constexpr int XPB  = 512 / NC4;
  constexpr int XPI  = (WOUT / 2) * WOUT;
  __shared__ float Wl[K * NTILE];          // 64 KB
  const int tid = threadIdx.x;
  const int cs  = blockIdx.y;
  constexpr int TOT4 = K * NC4;
  for (int i = tid; i < TOT4; i += 512) {
    int k = i / NC4, c4 = i % NC4;
    *(float4*)&Wl[k * NTILE + c4 * 4] =
        *(const float4*)&w[(size_t)k * COUT + cs * NTILE + c4 * 4];
  }
  __syncthreads();
  const int c4l  = tid % NC4;
  const int xpul = tid / NC4;
  int gxp = blockIdx.x * XPB + xpul;
  int n = gxp / XPI, r = gxp % XPI;
  int y = r / (WOUT / 2), xp = r % (WOUT / 2);
  const float* ip = in + (((size_t)n * WIN + 2 * y) * WIN + 4 * xp) * CIN;
  float4 bv = *(const float4*)(bias + cs * NTILE + c4l * 4);
  float4 a0 = bv, a1 = bv;
#pragma unroll
  for (int kk = 0; kk < 16; ++kk) {
    int ky = kk >> 2, kx = kk & 3;
    const float* ipr = ip + (ky * WIN + kx) * CIN;
    const float* wpr = Wl + kk * CIN * NTILE + c4l * 4;
#pragma unroll 4
    for (int ci4 = 0; ci4 < CIN / 4; ++ci4) {
      float4 i0 = *(const float4*)(ipr + ci4 * 4);
      float4 i1 = *(const float4*)(ipr + 2 * CIN + ci4 * 4);
      const float* wq = wpr + (size_t)(ci4 * 4) * NTILE;
      float4 w0 = *(const float4*)(wq);
      fma4(a0, i0.x, w0); fma4(a1, i1.x, w0);
      float4 w1v = *(const float4*)(wq + NTILE);
      fma4(a0, i0.y, w1v); fma4(a1, i1.y, w1v);
      float4 w2v = *(const float4*)(wq + 2 * NTILE);
      fma4(a0, i0.z, w2v); fma4(a1, i1.z, w2v);
      float4 w3v = *(const float4*)(wq + 3 * NTILE);
      fma4(a0, i0.w, w3v); fma4(a1, i1.w, w3v);
    }
  }
  int x0 = 2 * xp;
  float* op = out + (size_t)n * ostride + ((size_t)y * WOUT + x0) * COUT + cs * NTILE + c4l * 4;
  *(float4*)op          = relu4(a0);
  *(float4*)(op + COUT) = relu4(a1);
}

// ---- copy actions into xin columns 1024..1025 (row length 1026) ----
__global__ void act_copy(const float* __restrict__ act, float* __restrict__ xin) {
  int i = blockIdx.x * 256 + threadIdx.x;
  if (i < 2048) xin[(size_t)(i >> 1) * 1026 + 1024 + (i & 1)] = act[i];
}

// ---- xpart[t][b][2048] = xin[b*64+t][0..1026) @ k_l1[0..1026) + b_l1 ----
__global__ void gemm_xpart(const float* __restrict__ A, const float* __restrict__ Bw,
                           const float* __restrict__ bias, float* __restrict__ C) {
  __shared__ float As[16][64];
  __shared__ float Bs[16][64];
  const int tid = threadIdx.x;
  const int tx = tid & 15, ty = tid >> 4;
  const int m0 = blockIdx.y * 64, n0 = blockIdx.x * 64;
  float acc[4][4] = {};
  for (int k0 = 0; k0 < 1026; k0 += 16) {
#pragma unroll
    for (int i = 0; i < 4; ++i) {
      int lin = tid + i * 256;
      int ka = lin & 15, mm = lin >> 4;
      As[ka][mm] = (k0 + ka < 1026) ? A[(size_t)(m0 + mm) * 1026 + k0 + ka] : 0.0f;
      int kb = lin >> 6, nn = lin & 63;
      Bs[kb][nn] = (k0 + kb < 1026) ? Bw[(size_t)(k0 + kb) * 2048 + n0 + nn] : 0.0f;
    }
    __syncthreads();
#pragma unroll
    for (int kk = 0; kk < 16; ++kk) {
      float av[4], bv[4];
#pragma unroll
      for (int i = 0; i < 4; ++i) { av[i] = As[kk][ty * 4 + i]; bv[i] = Bs[kk][tx * 4 + i]; }
#pragma unroll
      for (int i = 0; i < 4; ++i)
#pragma unroll
        for (int j = 0; j < 4; ++j) acc[i][j] += av[i] * bv[j];
    }
    __syncthreads();
  }
#pragma unroll
  for (int i = 0; i < 4; ++i) {
    int m = m0 + ty * 4 + i;
    int xrow = (m & 63) * 16 + (m >> 6);   // (t, b)
#pragma unroll
    for (int j = 0; j < 4; ++j) {
      int n = n0 + tx * 4 + j;
      C[(size_t)xrow * 2048 + n] = acc[i][j] + bias[n];
    }
  }
}

// ---- persistent 2-layer LSTM: 64 blocks x 512 thr, weights in VGPRs,
//      one hand-rolled 2-level barrier per step ----
// L1: block owns u in [blk*8, +8) -> 32 v-cols c (u_l = c>>2, gate = c&3).
//     compute thread: c = tid&31, ks1 = tid>>5 (k-slice 32).
// L2: block owns u in [blk*4, +4) -> 16 v-cols.
//     compute thread: c = tid&15, ks2 = tid>>4 (k-slice 24 of 768).
// h layouts b-major: h1b [2][16][512], h2b [2][16][256].
__global__ void __launch_bounds__(512, 1)
lstm_k(const float* __restrict__ xpart,   // [64][16][2048] (incl b_l1)
       const float* __restrict__ kl1,     // [1538][2048]
       const float* __restrict__ kl2,     // [768][1024]
       const float* __restrict__ bl2,     // [1024]
       float* __restrict__ h1b, float* __restrict__ c1,
       float* __restrict__ h2b, float* __restrict__ c2,
       unsigned* __restrict__ bar,        // grp at [g*32], root at [256]
       float* __restrict__ out_seq) {     // [16][64][256]
  __shared__ float red1[4352];            // [8][32*17]
  __shared__ float gs1[544];              // [32][17]
  __shared__ float red2[2176];            // [8][16*17]
  __shared__ float gs2[272];              // [16][17]
  const int tid = threadIdx.x;
  const int blk = blockIdx.x;
  const float* Wh1 = kl1 + (size_t)1026 * 2048;

  const int cA  = tid & 31, ks1 = tid >> 5;       // L1 compute role
  const int k0A = ks1 * 32;
  const int pA  = (cA & 3) * 512 + blk * 8 + (cA >> 2);
  const int cB  = tid & 15, ks2 = tid >> 4;       // L2 compute role
  const int k0B = ks2 * 24;
  const int pB  = (cB & 3) * 256 + blk * 4 + (cB >> 2);
  const int cR  = tid >> 4, bR = tid & 15;        // reduce roles (L1: cR<32, L2: cR<16)
  const int pR1 = (cR & 3) * 512 + blk * 8 + (cR >> 2);
  const int pR2 = (cR & 3) * 256 + blk * 4 + (cR >> 2);

  // ---- one-time preloads ----
  float w1r[32], w2r[24];
#pragma unroll
  for (int i = 0; i < 32; ++i) w1r[i] = Wh1[(size_t)(k0A + i) * 2048 + pA];
#pragma unroll
  for (int i = 0; i < 24; ++i) w2r[i] = kl2[(size_t)(k0B + i) * 1024 + pB];
  const float blv = bl2[pR2];                     // valid-ish for all tid; used when cR<16

  for (int t = 0; t < 64; ++t) {
    const float* h1c = h1b + (size_t)(t & 1) * 8192;
    float* h1n       = h1b + (size_t)((t + 1) & 1) * 8192;
    const float* h2c = h2b + (size_t)(t & 1) * 4096;
    float* h2n       = h2b + (size_t)((t + 1) & 1) * 4096;

    // prefetch xpart value for the reduce role (used after first syncthreads)
    float xpv = xpart[(size_t)((t << 4) + bR) * 2048 + pR1];

    // ======== layer 1: gates = h1c @ Wh1 (+xpart) ========
    float acc[16];
#pragma unroll
    for (int b = 0; b < 16; ++b) acc[b] = 0.f;
#pragma unroll
    for (int bp = 0; bp < 8; ++bp) {
      const float* pa = h1c + (bp * 2) * 512 + k0A;
      const float* pb = pa + 512;
      float4 va[8], vb[8];
#pragma unroll
      for (int i = 0; i < 8; ++i) { va[i] = *(const float4*)(pa + i * 4); }
#pragma unroll
      for (int i = 0; i < 8; ++i) { vb[i] = *(const float4*)(pb + i * 4); }
      const float* fa = (const float*)va;
      const float* fb = (const float*)vb;
#pragma unroll
      for (int j = 0; j < 32; ++j) {
        acc[bp * 2]     = fmaf(w1r[j], fa[j], acc[bp * 2]);
        acc[bp * 2 + 1] = fmaf(w1r[j], fb[j], acc[bp * 2 + 1]);
      }
    }
    // fold ks1-pairs in-wave (xor 32), write 8 b's per lane
    {
      float fc[16];
#pragma unroll
      for (int b = 0; b < 16; ++b) fc[b] = acc[b] + __shfl_xor(acc[b], 32);
      int p = tid >> 6;                      // wave id = ks1>>1
      int half = (ks1 & 1) * 8;
      float* dst = red1 + p * 544 + cA * 17 + half;
#pragma unroll
      for (int j = 0; j < 8; ++j) dst[j] = fc[half + j];
    }
    __syncthreads();
    // final reduce: thread (cR<32, bR): sum 8 partials + xpart
    {
      float s = xpv;
#pragma unroll
      for (int p = 0; p < 8; ++p) s += red1[p * 544 + cR * 17 + bR];
      gs1[cR * 17 + bR] = s;
    }
    __syncthreads();
    if (tid < 128) {                         // cell update: (u_l = tid>>4, b = tid&15)
      int u_l = tid >> 4, b = tid & 15;
      int u = blk * 8 + u_l;
      float gi = gs1[(u_l * 4 + 0) * 17 + b];
      float gj = gs1[(u_l * 4 + 1) * 17 + b];
      float gf = gs1[(u_l * 4 + 2) * 17 + b];
      float go = gs1[(u_l * 4 + 3) * 17 + b];
      float cold = c1[b * 512 + u];
      float cn = sigm(gf + 1.0f) * cold + sigm(gi) * tanh_(gj);
      float hn = sigm(go) * tanh_(cn);
      c1[b * 512 + u] = cn;
      h1n[b * 512 + u] = hn;
    }
    __syncthreads();                         // cell writes drained (per-thread vmcnt)

    // ======== grid barrier: publish h1n ========
    if (tid == 0) {
      __threadfence();                       // release (L2 writeback)
      unsigned tgt = 8u * (t + 1);
      unsigned old = __hip_atomic_fetch_add(&bar[(blk >> 3) * 32], 1u,
                                            __ATOMIC_RELAXED, __HIP_MEMORY_SCOPE_AGENT);
      if (old == tgt - 1)
        __hip_atomic_fetch_add(&bar[256], 1u, __ATOMIC_RELAXED, __HIP_MEMORY_SCOPE_AGENT);
      while (__hip_atomic_load(&bar[256], __ATOMIC_RELAXED, __HIP_MEMORY_SCOPE_AGENT) < tgt)
        __builtin_amdgcn_s_sleep(4);
      __threadfence();                       // acquire (L1/L2 invalidate)
    }
    __syncthreads();

    // ======== layer 2: gates = [h1n ; h2c] @ kl2 ========
#pragma unroll
    for (int b = 0; b < 16; ++b) acc[b] = 0.f;
#pragma unroll
    for (int bp = 0; bp < 8; ++bp) {
      int b0 = bp * 2;
      float4 va[6], vb[6];
#pragma unroll
      for (int i = 0; i < 6; ++i) {
        int k = k0B + i * 4;
        va[i] = (k < 512) ? *(const float4*)(h1n + b0 * 512 + k)
                          : *(const float4*)(h2c + b0 * 256 + (k - 512));
      }
#pragma unroll
      for (int i = 0; i < 6; ++i) {
        int k = k0B + i * 4;
        vb[i] = (k < 512) ? *(const float4*)(h1n + (b0 + 1) * 512 + k)
                          : *(const float4*)(h2c + (b0 + 1) * 256 + (k - 512));
      }
      const float* fa = (const float*)va;
      const float* fb = (const float*)vb;
#pragma unroll
      for (int j = 0; j < 24; ++j) {
        acc[b0]     = fmaf(w2r[j], fa[j], acc[b0]);
        acc[b0 + 1] = fmaf(w2r[j], fb[j], acc[b0 + 1]);
      }
    }
    // fold ks2-quads (xor16 + xor32), lane (ks2&3) writes its b-quarter
    {
      float fc[16];
#pragma unroll
      for (int b = 0; b < 16; ++b) {
        float s = acc[b] + __shfl_xor(acc[b], 16);
        fc[b] = s + __shfl_xor(s, 32);
      }
      int q = tid >> 6;                      // wave id = ks2>>2
      int s4 = (ks2 & 3) * 4;
      float* dst = red2 + q * 272 + cB * 17 + s4;
#pragma unroll
      for (int j = 0; j < 4; ++j) dst[j] = fc[s4 + j];
    }
    __syncthreads();
    if (tid < 256) {                         // final reduce (cR<16, bR)
      float s = blv;
#pragma unroll
      for (int p = 0; p < 8; ++p) s += red2[p * 272 + cR * 17 + bR];
      gs2[cR * 17 + bR] = s;
    }
    __syncthreads();
    if (tid < 64) {                          // cell update: u = blk*4 + (tid>>4)
      int u_l = tid >> 4, b = tid & 15;
      int u = blk * 4 + u_l;
      float gi = gs2[(u_l * 4 + 0) * 17 + b];
      float gj = gs2[(u_l * 4 + 1) * 17 + b];
      float gf = gs2[(u_l * 4 + 2) * 17 + b];
      float go = gs2[(u_l * 4 + 3) * 17 + b];
      float cold = c2[b * 256 + u];
      float cn = sigm(gf + 1.0f) * cold + sigm(gi) * tanh_(gj);
      float hn = sigm(go) * tanh_(cn);
      c2[b * 256 + u] = cn;
      h2n[b * 256 + u] = hn;
      out_seq[(size_t)((b << 6) + t) * 256 + u] = hn;
    }
    // no second grid barrier: every block passes B(t+1) only after all blocks
    // finished L2(t) (program order), and h buffers are double-buffered.
  }
}

// ---- dense head: relu(lstm_out @ wd1 + bd1) @ wd2 + bd2 -> [1024] ----
__global__ void head_k(const float* __restrict__ xin, const float* __restrict__ wd1,
                       const float* __restrict__ bd1, const float* __restrict__ wd2,
                       const float* __restrict__ bd2, float* __restrict__ out) {
  __shared__ float xs[4][256];
  __shared__ float ps[4][128];
  int r0 = blockIdx.x * 4;
  int tid = threadIdx.x;
  for (int i = tid; i < 1024; i += 128) xs[i >> 8][i & 255] = xin[(size_t)r0 * 256 + i];
  __syncthreads();
  float w2 = wd2[tid];
  float bb = bd1[tid];
#pragma unroll
  for (int rr = 0; rr < 4; ++rr) {
    float acc = bb;
#pragma unroll 8
    for (int k = 0; k < 256; ++k) acc += xs[rr][k] * wd1[k * 128 + tid];
    ps[rr][tid] = fmaxf(acc, 0.0f) * w2;
  }
  __syncthreads();
  if (tid < 4) {
    float s = bd2[0];
    for (int k = 0; k < 128; ++k) s += ps[tid][k];
    out[r0 + tid] = s;
  }
}

extern "C" void kernel_launch(void* const* d_in, const int* in_sizes, int n_in,
                              void* d_out, int out_size, void* d_ws, size_t ws_size,
                              hipStream_t stream) {
  const float* frames  = (const float*)d_in[0];
  const float* actions = (const float*)d_in[1];
  const float* w1 = (const float*)d_in[2];   const float* b1 = (const float*)d_in[3];
  const float* w2 = (const float*)d_in[4];   const float* b2 = (const float*)d_in[5];
  const float* w3 = (const float*)d_in[6];   const float* b3 = (const float*)d_in[7];
  const float* w4 = (const float*)d_in[8];   const float* b4 = (const float*)d_in[9];
  const float* kl1 = (const float*)d_in[10]; const float* bl1 = (const float*)d_in[11];
  const float* kl2 = (const float*)d_in[12]; const float* bl2 = (const float*)d_in[13];
  const float* wd1 = (const float*)d_in[14]; const float* bd1 = (const float*)d_in[15];
  const float* wd2 = (const float*)d_in[16]; const float* bd2 = (const float*)d_in[17];
  float* out = (float*)d_out;

  float* ws = (float*)d_ws;
  float* a1    = ws;                 // [1024][31][31][32]
  float* a2    = ws + 31490048u;     // [1024][14][14][64]
  float* a3    = ws;                 // [1024][6][6][128]   (a1 dead)
  float* xin   = ws + 31490048u;     // [1024][1026]        (a2 dead)
  float* xpart = ws + 44335104u;     // [64][16][2048]
  float* h1b   = ws + 46432256u;     // [2][16][512]
  float* c1    = ws + 46448640u;     // [16][512]
  float* h2b   = ws + 46456832u;     // [2][16][256]
  float* c2    = ws + 46465024u;     // [16][256]
  unsigned* bar = (unsigned*)(ws + 46469120u);  // 512 words
  float* lout  = ws + 46469632u;     // [16][64][256]

  // zero h/c state + barrier counters (contiguous: 36864 + 512 floats)
  hipMemsetAsync(h1b, 0, (36864 + 512) * sizeof(float), stream);

  conv1_k4<<<15872, 256, 0, stream>>>(frames, w1, b1, a1);
  conv_lds<32, 64, 32, 31, 14><<<dim3(1568, 2), 512, 0, stream>>>(a1, w2, b2, a2, 14 * 14 * 64);
  conv_lds<64, 128, 16, 14, 6><<<dim3(144, 8), 512, 0, stream>>>(a2, w3, b3, a3, 6 * 6 * 128);
  conv_lds<128, 256, 8, 6, 2><<<dim3(8, 32), 512, 0, stream>>>(a3, w4, b4, xin, 1026);
  act_copy<<<8, 256, 0, stream>>>(actions, xin);
  gemm_xpart<<<dim3(32, 16), 256, 0, stream>>>(xin, kl1, bl1, xpart);

  void* args[10];
  args[0] = (void*)&xpart; args[1] = (void*)&kl1; args[2] = (void*)&kl2; args[3] = (void*)&bl2;
  args[4] = (void*)&h1b;   args[5] = (void*)&c1;  args[6] = (void*)&h2b; args[7] = (void*)&c2;
  args[8] = (void*)&bar;   args[9] = (void*)&lout;
  hipLaunchCooperativeKernel((void*)lstm_k, dim3(64), dim3(512), args, 0, stream);

  head_k<<<256, 128, 0, stream>>>(lout, wd1, bd1, wd2, bd2, out);
}

// Round 4
// 2772.529 us; speedup vs baseline: 1.6084x; 1.2597x over previous
//
#include <hip/hip_runtime.h>

#define DI __device__ __forceinline__

DI float sigm(float x)  { return 1.0f / (1.0f + __expf(-x)); }
DI float tanh_(float x) { return 2.0f / (1.0f + __expf(-2.0f * x)) - 1.0f; }

// cross-XCD-coherent scalar access (sc-bit load/store at the coherence point,
// NO cache writeback/invalidate -- the round-3 __threadfence nuked L2 every step)
DI float cload(const float* p) {
  return __hip_atomic_load(p, __ATOMIC_RELAXED, __HIP_MEMORY_SCOPE_AGENT);
}
DI void cstore(float* p, float v) {
  __hip_atomic_store(p, v, __ATOMIC_RELAXED, __HIP_MEMORY_SCOPE_AGENT);
}

DI void fma4(float4& a, float s, const float4& w) {
  a.x += s * w.x; a.y += s * w.y; a.z += s * w.z; a.w += s * w.w;
}
DI float4 relu4(float4 a) {
  return make_float4(fmaxf(a.x, 0.f), fmaxf(a.y, 0.f), fmaxf(a.z, 0.f), fmaxf(a.w, 0.f));
}

// ---------------- conv1: [1024,64,64,3] -> [1024,31,31,32], k4 s2 VALID, relu ----
__global__ void conv1_k4(const float* __restrict__ in, const float* __restrict__ w,
                         const float* __restrict__ bias, float* __restrict__ out) {
  int idx = blockIdx.x * 256 + threadIdx.x;
  if (idx >= 1024 * 31 * 16 * 8) return;
  int c4 = idx & 7;  int t = idx >> 3;
  int xp = t & 15;   t >>= 4;
  int y = t % 31;    int n = t / 31;
  const float* ip = in + (((size_t)n * 64 + 2 * y) * 64 + 4 * xp) * 3;
  bool v1 = (xp < 15);
  int off1 = v1 ? 6 : 0;
  float4 bv = *(const float4*)(bias + c4 * 4);
  float4 a0 = bv, a1 = bv;
#pragma unroll
  for (int ky = 0; ky < 4; ++ky) {
#pragma unroll
    for (int kx = 0; kx < 4; ++kx) {
      const float* ipr = ip + (ky * 64 + kx) * 3;
      const float* wp  = w + ((ky * 4 + kx) * 3) * 32 + c4 * 4;
#pragma unroll
      for (int ci = 0; ci < 3; ++ci) {
        float4 wv = *(const float4*)(wp + ci * 32);
        float i0 = ipr[ci], i1 = ipr[off1 + ci];
        fma4(a0, i0, wv);
        fma4(a1, i1, wv);
      }
    }
  }
  int x0 = 2 * xp;
  float* op = out + ((size_t)n * 31 * 31 + (size_t)y * 31 + x0) * 32 + c4 * 4;
  *(float4*)op = relu4(a0);
  if (v1) *(float4*)(op + 32) = relu4(a1);
}

// ---- k4 s2 VALID conv, weights in 64 KB LDS, TWO x-pairs per thread ----
// (second pair at +XPH amortizes the LDS weight reads: FMA:LDS issue ~2x round-3)
template <int CIN, int COUT, int NTILE, int WIN, int WOUT>
__global__ __launch_bounds__(512)
void conv_lds2(const float* __restrict__ in, const float* __restrict__ w,
               const float* __restrict__ bias, float* __restrict__ out, int ostride) {
  constexpr int K    = 16 * CIN;
  constexpr int NC4  = NTILE / 4;
  constexpr int XPB  = 512 / NC4;
  constexpr int XPI  = (WOUT / 2) * WOUT;
  constexpr int XPH  = 1024 * XPI / 2;
  __shared__ float Wl[K * NTILE];          // 64 KB
  const int tid = threadIdx.x;
  const int cs  = blockIdx.y;
  constexpr int TOT4 = K * NC4;
  for (int i = tid; i < TOT4; i += 512) {
    int k = i / NC4, c4 = i % NC4;
    *(float4*)&Wl[k * NTILE + c4 * 4] =
        *(const float4*)&w[(size_t)k * COUT + cs * NTILE + c4 * 4];
  }
  __syncthreads();
  const int c4l  = tid % NC4;
  const int xpul = tid / NC4;
  int g0 = blockIdx.x * XPB + xpul;
  int g1 = g0 + XPH;
  int n0 = g0 / XPI, r0 = g0 % XPI;
  int y0 = r0 / (WOUT / 2), xp0 = r0 % (WOUT / 2);
  int n1 = g1 / XPI, r1 = g1 % XPI;
  int y1 = r1 / (WOUT / 2), xp1 = r1 % (WOUT / 2);
  const float* ip0 = in + (((size_t)n0 * WIN + 2 * y0) * WIN + 4 * xp0) * CIN;
  const float* ip1 = in + (((size_t)n1 * WIN + 2 * y1) * WIN + 4 * xp1) * CIN;
  float4 bv = *(const float4*)(bias + cs * NTILE + c4l * 4);
  float4 a00 = bv, a01 = bv, a10 = bv, a11 = bv;
#pragma unroll
  for (int kk = 0; kk < 16; ++kk) {
    int ky = kk >> 2, kx = kk & 3;
    const float* i0r = ip0 + (ky * WIN + kx) * CIN;
    const float* i1r = ip1 + (ky * WIN + kx) * CIN;
    const float* wpr = Wl + kk * CIN * NTILE + c4l * 4;
#pragma unroll 4
    for (int ci4 = 0; ci4 < CIN / 4; ++ci4) {
      float4 p00 = *(const float4*)(i0r + ci4 * 4);
      float4 p01 = *(const float4*)(i0r + 2 * CIN + ci4 * 4);
      float4 p10 = *(const float4*)(i1r + ci4 * 4);
      float4 p11 = *(const float4*)(i1r + 2 * CIN + ci4 * 4);
      const float* wq = wpr + (size_t)(ci4 * 4) * NTILE;
      float4 w0 = *(const float4*)(wq);
      fma4(a00, p00.x, w0); fma4(a01, p01.x, w0); fma4(a10, p10.x, w0); fma4(a11, p11.x, w0);
      float4 w1v = *(const float4*)(wq + NTILE);
      fma4(a00, p00.y, w1v); fma4(a01, p01.y, w1v); fma4(a10, p10.y, w1v); fma4(a11, p11.y, w1v);
      float4 w2v = *(const float4*)(wq + 2 * NTILE);
      fma4(a00, p00.z, w2v); fma4(a01, p01.z, w2v); fma4(a10, p10.z, w2v); fma4(a11, p11.z, w2v);
      float4 w3v = *(const float4*)(wq + 3 * NTILE);
      fma4(a00, p00.w, w3v); fma4(a01, p01.w, w3v); fma4(a10, p10.w, w3v); fma4(a11, p11.w, w3v);
    }
  }
  float* o0 = out + (size_t)n0 * ostride + ((size_t)y0 * WOUT + 2 * xp0) * COUT + cs * NTILE + c4l * 4;
  *(float4*)o0          = relu4(a00);
  *(float4*)(o0 + COUT) = relu4(a01);
  float* o1 = out + (size_t)n1 * ostride + ((size_t)y1 * WOUT + 2 * xp1) * COUT + cs * NTILE + c4l * 4;
  *(float4*)o1          = relu4(a10);
  *(float4*)(o1 + COUT) = relu4(a11);
}

// ---- copy actions into xin columns 1024..1025 (row length 1026) ----
__global__ void act_copy(const float* __restrict__ act, float* __restrict__ xin) {
  int i = blockIdx.x * 256 + threadIdx.x;
  if (i < 2048) xin[(size_t)(i >> 1) * 1026 + 1024 + (i & 1)] = act[i];
}

// ---- xpart[t][b][2048] = xin[b*64+t][0..1026) @ k_l1[0..1026) + b_l1 ----
__global__ void gemm_xpart(const float* __restrict__ A, const float* __restrict__ Bw,
                           const float* __restrict__ bias, float* __restrict__ C) {
  __shared__ float As[16][64];
  __shared__ float Bs[16][64];
  const int tid = threadIdx.x;
  const int tx = tid & 15, ty = tid >> 4;
  const int m0 = blockIdx.y * 64, n0 = blockIdx.x * 64;
  float acc[4][4] = {};
  for (int k0 = 0; k0 < 1026; k0 += 16) {
#pragma unroll
    for (int i = 0; i < 4; ++i) {
      int lin = tid + i * 256;
      int ka = lin & 15, mm = lin >> 4;
      As[ka][mm] = (k0 + ka < 1026) ? A[(size_t)(m0 + mm) * 1026 + k0 + ka] : 0.0f;
      int kb = lin >> 6, nn = lin & 63;
      Bs[kb][nn] = (k0 + kb < 1026) ? Bw[(size_t)(k0 + kb) * 2048 + n0 + nn] : 0.0f;
    }
    __syncthreads();
#pragma unroll
    for (int kk = 0; kk < 16; ++kk) {
      float av[4], bv[4];
#pragma unroll
      for (int i = 0; i < 4; ++i) { av[i] = As[kk][ty * 4 + i]; bv[i] = Bs[kk][tx * 4 + i]; }
#pragma unroll
      for (int i = 0; i < 4; ++i)
#pragma unroll
        for (int j = 0; j < 4; ++j) acc[i][j] += av[i] * bv[j];
    }
    __syncthreads();
  }
#pragma unroll
  for (int i = 0; i < 4; ++i) {
    int m = m0 + ty * 4 + i;
    int xrow = (m & 63) * 16 + (m >> 6);   // (t, b)
#pragma unroll
    for (int j = 0; j < 4; ++j) {
      int n = n0 + tx * 4 + j;
      C[(size_t)xrow * 2048 + n] = acc[i][j] + bias[n];
    }
  }
}

// ---- persistent 2-layer LSTM: 64 blocks x 512 thr, weights in VGPRs.
// Cross-block h exchange via coherent (agent-scope relaxed atomic) loads/stores
// staged through LDS; NO cache-flushing fences. One 2-level barrier per step.
__global__ void __launch_bounds__(512, 1)
lstm_k(const float* __restrict__ xpart,   // [64][16][2048] (incl b_l1)
       const float* __restrict__ kl1,     // [1538][2048]
       const float* __restrict__ kl2,     // [768][1024]
       const float* __restrict__ bl2,     // [1024]
       float* __restrict__ h1b, float* __restrict__ c1,
       float* __restrict__ h2b, float* __restrict__ c2,
       unsigned* __restrict__ bar,        // grp at [g*32], root at [256]
       float* __restrict__ out_seq) {     // [16][64][256]
  __shared__ float big[12544];            // L1: stg1[0..8192)+red1[8192..12544) ; L2: stg2[0..12288)
  __shared__ float red2[2176];
  __shared__ float gs1[544];
  __shared__ float gs2[272];
  float* stg1 = big;
  float* red1 = big + 8192;
  float* stg2 = big;
  const int tid = threadIdx.x;
  const int blk = blockIdx.x;
  const float* Wh1 = kl1 + (size_t)1026 * 2048;

  const int cA  = tid & 31, ks1 = tid >> 5;       // L1 compute role
  const int k0A = ks1 * 32;
  const int pA  = (cA & 3) * 512 + blk * 8 + (cA >> 2);
  const int cB  = tid & 15, ks2 = tid >> 4;       // L2 compute role
  const int k0B = ks2 * 24;
  const int pB  = (cB & 3) * 256 + blk * 4 + (cB >> 2);
  const int cR  = tid >> 4, bR = tid & 15;        // reduce roles
  const int pR1 = (cR & 3) * 512 + blk * 8 + (cR >> 2);
  const int pR2 = (cR & 3) * 256 + blk * 4 + (cR >> 2);

  // ---- one-time weight preloads (normal cached) ----
  float w1r[32], w2r[24];
#pragma unroll
  for (int i = 0; i < 32; ++i) w1r[i] = Wh1[(size_t)(k0A + i) * 2048 + pA];
#pragma unroll
  for (int i = 0; i < 24; ++i) w2r[i] = kl2[(size_t)(k0B + i) * 1024 + pB];
  const float blv = bl2[pR2];

  for (int t = 0; t < 64; ++t) {
    const float* h1c = h1b + (size_t)(t & 1) * 8192;
    float* h1n       = h1b + (size_t)((t + 1) & 1) * 8192;
    const float* h2c = h2b + (size_t)(t & 1) * 4096;
    float* h2n       = h2b + (size_t)((t + 1) & 1) * 4096;

    float xpv = xpart[(size_t)((t << 4) + bR) * 2048 + pR1];   // normal, L2-warm

    // ---- stage h1c -> stg1 [16][512] via coherent loads ----
    float sv[16];
#pragma unroll
    for (int j = 0; j < 16; ++j) sv[j] = cload(h1c + (j << 9) + tid);
    __syncthreads();                       // prev-iter stg2/gs2 consumers done
#pragma unroll
    for (int j = 0; j < 16; ++j) stg1[(j << 9) + tid] = sv[j];
    __syncthreads();

    // ======== layer 1: gates = h1c @ Wh1 (+xpart) ========
    float acc[16];
#pragma unroll
    for (int b = 0; b < 16; ++b) acc[b] = 0.f;
#pragma unroll
    for (int bp = 0; bp < 8; ++bp) {
      const float* pa = stg1 + (bp * 2) * 512 + k0A;
      const float* pb = pa + 512;
      float4 va[8], vb[8];
#pragma unroll
      for (int i = 0; i < 8; ++i) va[i] = *(const float4*)(pa + i * 4);
#pragma unroll
      for (int i = 0; i < 8; ++i) vb[i] = *(const float4*)(pb + i * 4);
      const float* fa = (const float*)va;
      const float* fb = (const float*)vb;
#pragma unroll
      for (int j = 0; j < 32; ++j) {
        acc[bp * 2]     = fmaf(w1r[j], fa[j], acc[bp * 2]);
        acc[bp * 2 + 1] = fmaf(w1r[j], fb[j], acc[bp * 2 + 1]);
      }
    }
    {
      float fc[16];
#pragma unroll
      for (int b = 0; b < 16; ++b) fc[b] = acc[b] + __shfl_xor(acc[b], 32);
      int p = tid >> 6;
      int half = (ks1 & 1) * 8;
      float* dst = red1 + p * 544 + cA * 17 + half;
#pragma unroll
      for (int j = 0; j < 8; ++j) dst[j] = fc[half + j];
    }
    __syncthreads();
    {
      float s = xpv;
#pragma unroll
      for (int p = 0; p < 8; ++p) s += red1[p * 544 + cR * 17 + bR];
      gs1[cR * 17 + bR] = s;
    }
    __syncthreads();
    if (tid < 128) {                       // cell update: (u_l = tid>>4, b = tid&15)
      int u_l = tid >> 4, b = tid & 15;
      int u = blk * 8 + u_l;
      float gi = gs1[(u_l * 4 + 0) * 17 + b];
      float gj = gs1[(u_l * 4 + 1) * 17 + b];
      float gf = gs1[(u_l * 4 + 2) * 17 + b];
      float go = gs1[(u_l * 4 + 3) * 17 + b];
      float cold = c1[b * 512 + u];        // block-private, normal cached
      float cn = sigm(gf + 1.0f) * cold + sigm(gi) * tanh_(gj);
      float hn = sigm(go) * tanh_(cn);
      c1[b * 512 + u] = cn;
      cstore(h1n + b * 512 + u, hn);       // coherent publish
    }
    __syncthreads();                       // drains vmcnt: coherent stores ack'd

    // ======== grid barrier (relaxed atomics only, no cache flush) ========
    if (tid == 0) {
      unsigned tgt = 8u * (t + 1);
      unsigned old = __hip_atomic_fetch_add(&bar[(blk >> 3) * 32], 1u,
                                            __ATOMIC_RELAXED, __HIP_MEMORY_SCOPE_AGENT);
      if (old == tgt - 1)
        __hip_atomic_fetch_add(&bar[256], 1u, __ATOMIC_RELAXED, __HIP_MEMORY_SCOPE_AGENT);
      while (__hip_atomic_load(&bar[256], __ATOMIC_RELAXED, __HIP_MEMORY_SCOPE_AGENT) < tgt)
        __builtin_amdgcn_s_sleep(2);
    }
    __syncthreads();

    // ---- stage [h1n ; h2c] -> stg2 [16][768] via coherent loads ----
    float sw[24];
#pragma unroll
    for (int j = 0; j < 24; ++j) {
      int e = (j << 9) + tid;
      sw[j] = (j < 16) ? cload(h1n + e) : cload(h2c + (e - 8192));
    }
#pragma unroll
    for (int j = 0; j < 24; ++j) {
      if (j < 16) stg2[j * 768 + tid] = sw[j];
      else {
        int b = (j - 16) * 2 + (tid >> 8);
        stg2[b * 768 + 512 + (tid & 255)] = sw[j];
      }
    }
    __syncthreads();

    // ======== layer 2: gates = [h1n ; h2c] @ kl2 ========
#pragma unroll
    for (int b = 0; b < 16; ++b) acc[b] = 0.f;
#pragma unroll
    for (int bp = 0; bp < 8; ++bp) {
      const float* pa = stg2 + (bp * 2) * 768 + k0B;
      const float* pb = pa + 768;
      float4 va[6], vb[6];
#pragma unroll
      for (int i = 0; i < 6; ++i) va[i] = *(const float4*)(pa + i * 4);
#pragma unroll
      for (int i = 0; i < 6; ++i) vb[i] = *(const float4*)(pb + i * 4);
      const float* fa = (const float*)va;
      const float* fb = (const float*)vb;
#pragma unroll
      for (int j = 0; j < 24; ++j) {
        acc[bp * 2]     = fmaf(w2r[j], fa[j], acc[bp * 2]);
        acc[bp * 2 + 1] = fmaf(w2r[j], fb[j], acc[bp * 2 + 1]);
      }
    }
    {
      float fc[16];
#pragma unroll
      for (int b = 0; b < 16; ++b) {
        float s = acc[b] + __shfl_xor(acc[b], 16);
        fc[b] = s + __shfl_xor(s, 32);
      }
      int q = tid >> 6;
      int s4 = (ks2 & 3) * 4;
      float* dst = red2 + q * 272 + cB * 17 + s4;
#pragma unroll
      for (int j = 0; j < 4; ++j) dst[j] = fc[s4 + j];
    }
    __syncthreads();
    if (tid < 256) {
      float s = blv;
#pragma unroll
      for (int p = 0; p < 8; ++p) s += red2[p * 272 + cR * 17 + bR];
      gs2[cR * 17 + bR] = s;
    }
    __syncthreads();
    if (tid < 64) {                        // cell update, u = blk*4 + (tid>>4)
      int u_l = tid >> 4, b = tid & 15;
      int u = blk * 4 + u_l;
      float gi = gs2[(u_l * 4 + 0) * 17 + b];
      float gj = gs2[(u_l * 4 + 1) * 17 + b];
      float gf = gs2[(u_l * 4 + 2) * 17 + b];
      float go = gs2[(u_l * 4 + 3) * 17 + b];
      float cold = c2[b * 256 + u];        // block-private, normal cached
      float cn = sigm(gf + 1.0f) * cold + sigm(gi) * tanh_(gj);
      float hn = sigm(go) * tanh_(cn);
      c2[b * 256 + u] = cn;
      cstore(h2n + b * 256 + u, hn);       // coherent publish
      out_seq[(size_t)((b << 6) + t) * 256 + u] = hn;   // normal; flushed at kernel end
    }
    // next-iter loop-top __syncthreads guards stg reuse; reads of this step's
    // buffers complete (data-dependency) before each block's next arrive.
  }
}

// ---- dense head: relu(lstm_out @ wd1 + bd1) @ wd2 + bd2 -> [1024] ----
__global__ void head_k(const float* __restrict__ xin, const float* __restrict__ wd1,
                       const float* __restrict__ bd1, const float* __restrict__ wd2,
                       const float* __restrict__ bd2, float* __restrict__ out) {
  __shared__ float xs[4][256];
  __shared__ float ps[4][128];
  int r0 = blockIdx.x * 4;
  int tid = threadIdx.x;
  for (int i = tid; i < 1024; i += 128) xs[i >> 8][i & 255] = xin[(size_t)r0 * 256 + i];
  __syncthreads();
  float w2 = wd2[tid];
  float bb = bd1[tid];
#pragma unroll
  for (int rr = 0; rr < 4; ++rr) {
    float acc = bb;
#pragma unroll 8
    for (int k = 0; k < 256; ++k) acc += xs[rr][k] * wd1[k * 128 + tid];
    ps[rr][tid] = fmaxf(acc, 0.0f) * w2;
  }
  __syncthreads();
  if (tid < 4) {
    float s = bd2[0];
    for (int k = 0; k < 128; ++k) s += ps[tid][k];
    out[r0 + tid] = s;
  }
}

extern "C" void kernel_launch(void* const* d_in, const int* in_sizes, int n_in,
                              void* d_out, int out_size, void* d_ws, size_t ws_size,
                              hipStream_t stream) {
  const float* frames  = (const float*)d_in[0];
  const float* actions = (const float*)d_in[1];
  const float* w1 = (const float*)d_in[2];   const float* b1 = (const float*)d_in[3];
  const float* w2 = (const float*)d_in[4];   const float* b2 = (const float*)d_in[5];
  const float* w3 = (const float*)d_in[6];   const float* b3 = (const float*)d_in[7];
  const float* w4 = (const float*)d_in[8];   const float* b4 = (const float*)d_in[9];
  const float* kl1 = (const float*)d_in[10]; const float* bl1 = (const float*)d_in[11];
  const float* kl2 = (const float*)d_in[12]; const float* bl2 = (const float*)d_in[13];
  const float* wd1 = (const float*)d_in[14]; const float* bd1 = (const float*)d_in[15];
  const float* wd2 = (const float*)d_in[16]; const float* bd2 = (const float*)d_in[17];
  float* out = (float*)d_out;

  float* ws = (float*)d_ws;
  float* a1    = ws;                 // [1024][31][31][32]
  float* a2    = ws + 31490048u;     // [1024][14][14][64]
  float* a3    = ws;                 // [1024][6][6][128]   (a1 dead)
  float* xin   = ws + 31490048u;     // [1024][1026]        (a2 dead)
  float* xpart = ws + 44335104u;     // [64][16][2048]
  float* h1b   = ws + 46432256u;     // [2][16][512]
  float* c1    = ws + 46448640u;     // [16][512]
  float* h2b   = ws + 46456832u;     // [2][16][256]
  float* c2    = ws + 46465024u;     // [16][256]
  unsigned* bar = (unsigned*)(ws + 46469120u);  // 512 words
  float* lout  = ws + 46469632u;     // [16][64][256]

  hipMemsetAsync(h1b, 0, (36864 + 512) * sizeof(float), stream);

  conv1_k4<<<15872, 256, 0, stream>>>(frames, w1, b1, a1);
  conv_lds2<32, 64, 32, 31, 14><<<dim3(784, 2), 512, 0, stream>>>(a1, w2, b2, a2, 14 * 14 * 64);
  conv_lds2<64, 128, 16, 14, 6><<<dim3(72, 8), 512, 0, stream>>>(a2, w3, b3, a3, 6 * 6 * 128);
  conv_lds2<128, 256, 8, 6, 2><<<dim3(4, 32), 512, 0, stream>>>(a3, w4, b4, xin, 1026);
  act_copy<<<8, 256, 0, stream>>>(actions, xin);
  gemm_xpart<<<dim3(32, 16), 256, 0, stream>>>(xin, kl1, bl1, xpart);

  void* args[10];
  args[0] = (void*)&xpart; args[1] = (void*)&kl1; args[2] = (void*)&kl2; args[3] = (void*)&bl2;
  args[4] = (void*)&h1b;   args[5] = (void*)&c1;  args[6] = (void*)&h2b; args[7] = (void*)&c2;
  args[8] = (void*)&bar;   args[9] = (void*)&lout;
  hipLaunchCooperativeKernel((void*)lstm_k, dim3(64), dim3(512), args, 0, stream);

  head_k<<<256, 128, 0, stream>>>(lout, wd1, bd1, wd2, bd2, out);
}

// Round 6
// 2600.580 us; speedup vs baseline: 1.7147x; 1.0661x over previous
//
#include <hip/hip_runtime.h>

#define DI __device__ __forceinline__

DI float sigm(float x)  { return 1.0f / (1.0f + __expf(-x)); }
DI float tanh_(float x) { return 2.0f / (1.0f + __expf(-2.0f * x)) - 1.0f; }

// cross-XCD-coherent accesses (point-coherent at Infinity Cache; no cache flush)
DI float cload(const float* p) {
  return __hip_atomic_load(p, __ATOMIC_RELAXED, __HIP_MEMORY_SCOPE_AGENT);
}
DI void cstore(float* p, float v) {
  __hip_atomic_store(p, v, __ATOMIC_RELAXED, __HIP_MEMORY_SCOPE_AGENT);
}
DI unsigned uload(const unsigned* p) {
  return __hip_atomic_load(p, __ATOMIC_RELAXED, __HIP_MEMORY_SCOPE_AGENT);
}
DI void ustore(unsigned* p, unsigned v) {
  __hip_atomic_store(p, v, __ATOMIC_RELAXED, __HIP_MEMORY_SCOPE_AGENT);
}

DI void fma4(float4& a, float s, const float4& w) {
  a.x += s * w.x; a.y += s * w.y; a.z += s * w.z; a.w += s * w.w;
}
DI float4 relu4(float4 a) {
  return make_float4(fmaxf(a.x, 0.f), fmaxf(a.y, 0.f), fmaxf(a.z, 0.f), fmaxf(a.w, 0.f));
}

// ---------------- conv1: [1024,64,64,3] -> [1024,31,31,32], k4 s2 VALID, relu ----
__global__ void conv1_k4(const float* __restrict__ in, const float* __restrict__ w,
                         const float* __restrict__ bias, float* __restrict__ out) {
  int idx = blockIdx.x * 256 + threadIdx.x;
  if (idx >= 1024 * 31 * 16 * 8) return;
  int c4 = idx & 7;  int t = idx >> 3;
  int xp = t & 15;   t >>= 4;
  int y = t % 31;    int n = t / 31;
  const float* ip = in + (((size_t)n * 64 + 2 * y) * 64 + 4 * xp) * 3;
  bool v1 = (xp < 15);
  int off1 = v1 ? 6 : 0;
  float4 bv = *(const float4*)(bias + c4 * 4);
  float4 a0 = bv, a1 = bv;
#pragma unroll
  for (int ky = 0; ky < 4; ++ky) {
#pragma unroll
    for (int kx = 0; kx < 4; ++kx) {
      const float* ipr = ip + (ky * 64 + kx) * 3;
      const float* wp  = w + ((ky * 4 + kx) * 3) * 32 + c4 * 4;
#pragma unroll
      for (int ci = 0; ci < 3; ++ci) {
        float4 wv = *(const float4*)(wp + ci * 32);
        float i0 = ipr[ci], i1 = ipr[off1 + ci];
        fma4(a0, i0, wv);
        fma4(a1, i1, wv);
      }
    }
  }
  int x0 = 2 * xp;
  float* op = out + ((size_t)n * 31 * 31 + (size_t)y * 31 + x0) * 32 + c4 * 4;
  *(float4*)op = relu4(a0);
  if (v1) *(float4*)(op + 32) = relu4(a1);
}

// ---- k4 s2 VALID conv: weights in 64 KB LDS; one x-pair/thread; inputs
// software-prefetched one (ky,ci4) iteration ahead; 6-col loads serve 4kx x 2pos ----
template <int CIN, int COUT, int NTILE, int WIN, int WOUT>
__global__ __launch_bounds__(512)
void conv_lds3(const float* __restrict__ in, const float* __restrict__ w,
               const float* __restrict__ bias, float* __restrict__ out, int ostride) {
  constexpr int K    = 16 * CIN;
  constexpr int NC4  = NTILE / 4;
  constexpr int XPB  = 512 / NC4;
  constexpr int XPI  = (WOUT / 2) * WOUT;
  constexpr int C4N  = CIN / 4;            // power of 2
  constexpr int NIT  = 4 * C4N;
  __shared__ float Wl[K * NTILE];          // 64 KB
  const int tid = threadIdx.x;
  const int cs  = blockIdx.y;
  constexpr int TOT4 = K * NC4;
  for (int i = tid; i < TOT4; i += 512) {
    int k = i / NC4, c4 = i % NC4;
    *(float4*)&Wl[k * NTILE + c4 * 4] =
        *(const float4*)&w[(size_t)k * COUT + cs * NTILE + c4 * 4];
  }
  __syncthreads();
  const int c4l  = tid % NC4;
  const int xpul = tid / NC4;
  int gxp = blockIdx.x * XPB + xpul;
  int n = gxp / XPI, r = gxp % XPI;
  int y = r / (WOUT / 2), xp = r % (WOUT / 2);
  const float* ip = in + (((size_t)n * WIN + 2 * y) * WIN + 4 * xp) * CIN;
  float4 bv = *(const float4*)(bias + cs * NTILE + c4l * 4);
  float4 a0 = bv, a1 = bv;

  float4 cur[6], nxt[6];
#pragma unroll
  for (int cc = 0; cc < 6; ++cc) cur[cc] = *(const float4*)(ip + cc * CIN);
#pragma unroll 2
  for (int it = 0; it < NIT; ++it) {
    int ky = it / C4N, ci4 = it % C4N;
    if (it + 1 < NIT) {
      int ky2 = (it + 1) / C4N, ci42 = (it + 1) % C4N;
      const float* base = ip + (ky2 * WIN) * CIN + ci42 * 4;
#pragma unroll
      for (int cc = 0; cc < 6; ++cc) nxt[cc] = *(const float4*)(base + cc * CIN);
    }
    const float* wr = Wl + ((ky * 4) * CIN + ci4 * 4) * NTILE + c4l * 4;
#pragma unroll
    for (int kx = 0; kx < 4; ++kx) {
      const float* wq = wr + (size_t)kx * CIN * NTILE;
      float4 w0 = *(const float4*)(wq);
      fma4(a0, cur[kx].x, w0);     fma4(a1, cur[kx + 2].x, w0);
      float4 w1v = *(const float4*)(wq + NTILE);
      fma4(a0, cur[kx].y, w1v);    fma4(a1, cur[kx + 2].y, w1v);
      float4 w2v = *(const float4*)(wq + 2 * NTILE);
      fma4(a0, cur[kx].z, w2v);    fma4(a1, cur[kx + 2].z, w2v);
      float4 w3v = *(const float4*)(wq + 3 * NTILE);
      fma4(a0, cur[kx].w, w3v);    fma4(a1, cur[kx + 2].w, w3v);
    }
#pragma unroll
    for (int cc = 0; cc < 6; ++cc) cur[cc] = nxt[cc];
  }
  float* op = out + (size_t)n * ostride + ((size_t)y * WOUT + 2 * xp) * COUT + cs * NTILE + c4l * 4;
  *(float4*)op          = relu4(a0);
  *(float4*)(op + COUT) = relu4(a1);
}

// ---- copy actions into xin columns 1024..1025 (row length 1026) ----
__global__ void act_copy(const float* __restrict__ act, float* __restrict__ xin) {
  int i = blockIdx.x * 256 + threadIdx.x;
  if (i < 2048) xin[(size_t)(i >> 1) * 1026 + 1024 + (i & 1)] = act[i];
}

// ---- xpart[t][b][2048] = xin[b*64+t][0..1026) @ k_l1[0..1026) + b_l1 ----
__global__ void gemm_xpart(const float* __restrict__ A, const float* __restrict__ Bw,
                           const float* __restrict__ bias, float* __restrict__ C) {
  __shared__ float As[16][64];
  __shared__ float Bs[16][64];
  const int tid = threadIdx.x;
  const int tx = tid & 15, ty = tid >> 4;
  const int m0 = blockIdx.y * 64, n0 = blockIdx.x * 64;
  float acc[4][4] = {};
  for (int k0 = 0; k0 < 1026; k0 += 16) {
#pragma unroll
    for (int i = 0; i < 4; ++i) {
      int lin = tid + i * 256;
      int ka = lin & 15, mm = lin >> 4;
      As[ka][mm] = (k0 + ka < 1026) ? A[(size_t)(m0 + mm) * 1026 + k0 + ka] : 0.0f;
      int kb = lin >> 6, nn = lin & 63;
      Bs[kb][nn] = (k0 + kb < 1026) ? Bw[(size_t)(k0 + kb) * 2048 + n0 + nn] : 0.0f;
    }
    __syncthreads();
#pragma unroll
    for (int kk = 0; kk < 16; ++kk) {
      float av[4], bv[4];
#pragma unroll
      for (int i = 0; i < 4; ++i) { av[i] = As[kk][ty * 4 + i]; bv[i] = Bs[kk][tx * 4 + i]; }
#pragma unroll
      for (int i = 0; i < 4; ++i)
#pragma unroll
        for (int j = 0; j < 4; ++j) acc[i][j] += av[i] * bv[j];
    }
    __syncthreads();
  }
#pragma unroll
  for (int i = 0; i < 4; ++i) {
    int m = m0 + ty * 4 + i;
    int xrow = (m & 63) * 16 + (m >> 6);   // (t, b)
#pragma unroll
    for (int j = 0; j < 4; ++j) {
      int n = n0 + tx * 4 + j;
      C[(size_t)xrow * 2048 + n] = acc[i][j] + bias[n];
    }
  }
}

// ---- persistent 2-layer LSTM, PIPELINED across block groups ----
// 80 blocks x 512 thr: blocks 0..63 compute layer 1 (8 u each), blocks 64..79
// compute layer 2 (16 u each) one step behind. Sync via coherent epoch flags:
//   flag1[i] = L1 block i finished step flag1[i]-1 (h1n published)
//   flag2[j] = L2 block j finished step flag2[j]-1 (h2n published, inputs staged)
// L1 end-of-step-t spin: flag1[*] >= t+1 (h1 complete) && flag2[*] >= t
//   (L2 staged step-(t-1) inputs -> safe to overwrite h1b[t&1] next step).
// L2 start-of-step-s spin: flag1[*] >= s+1 (h1n(s) ready) && flag2[*] >= s
//   (h2b[s&1] complete; nobody overwrites it until all pass flag2 >= s+1).
__global__ void __launch_bounds__(512, 1)
lstm_k(const float* __restrict__ xpart,   // [64][16][2048] (incl b_l1)
       const float* __restrict__ kl1,     // [1538][2048]
       const float* __restrict__ kl2,     // [768][1024]
       const float* __restrict__ bl2,     // [1024]
       float* __restrict__ h1b, float* __restrict__ c1,
       float* __restrict__ h2b, float* __restrict__ c2,
       unsigned* __restrict__ flg,        // flag1 = flg[0..63], flag2 = flg[64..79]
       float* __restrict__ out_seq) {     // [16][64][256]
  __shared__ float big[12544];
  __shared__ float gs1[544];
  __shared__ float gs2[1088];
  const int tid = threadIdx.x;
  const int blk = blockIdx.x;
  unsigned* flag1 = flg;
  unsigned* flag2 = flg + 64;

  if (blk < 64) {
    // ================= layer-1 blocks =================
    float* stg1 = big;                     // [16][512]
    float* red1 = big + 8192;              // [8][32*17]
    const float* Wh1 = kl1 + (size_t)1026 * 2048;
    const int cA  = tid & 31, ks1 = tid >> 5;
    const int k0A = ks1 * 32;
    const int pA  = (cA & 3) * 512 + blk * 8 + (cA >> 2);
    const int cR  = tid >> 4, bR = tid & 15;
    const int pR1 = (cR & 3) * 512 + blk * 8 + (cR >> 2);
    float w1r[32];
#pragma unroll
    for (int i = 0; i < 32; ++i) w1r[i] = Wh1[(size_t)(k0A + i) * 2048 + pA];

    for (int t = 0; t < 64; ++t) {
      const float* h1c = h1b + (size_t)(t & 1) * 8192;
      float* h1n       = h1b + (size_t)((t + 1) & 1) * 8192;
      float xpv = xpart[(size_t)((t << 4) + bR) * 2048 + pR1];   // normal cached

      float sv[16];
#pragma unroll
      for (int j = 0; j < 16; ++j) sv[j] = cload(h1c + (j << 9) + tid);
#pragma unroll
      for (int j = 0; j < 16; ++j) stg1[(j << 9) + tid] = sv[j];
      __syncthreads();

      float acc[16];
#pragma unroll
      for (int b = 0; b < 16; ++b) acc[b] = 0.f;
#pragma unroll
      for (int bp = 0; bp < 8; ++bp) {
        const float* pa = stg1 + (bp * 2) * 512 + k0A;
        const float* pb = pa + 512;
        float4 va[8], vb[8];
#pragma unroll
        for (int i = 0; i < 8; ++i) va[i] = *(const float4*)(pa + i * 4);
#pragma unroll
        for (int i = 0; i < 8; ++i) vb[i] = *(const float4*)(pb + i * 4);
        const float* fa = (const float*)va;
        const float* fb = (const float*)vb;
#pragma unroll
        for (int j = 0; j < 32; ++j) {
          acc[bp * 2]     = fmaf(w1r[j], fa[j], acc[bp * 2]);
          acc[bp * 2 + 1] = fmaf(w1r[j], fb[j], acc[bp * 2 + 1]);
        }
      }
      {
        float fc[16];
#pragma unroll
        for (int b = 0; b < 16; ++b) fc[b] = acc[b] + __shfl_xor(acc[b], 32);
        int p = tid >> 6;
        int half = (ks1 & 1) * 8;
        float* dst = red1 + p * 544 + cA * 17 + half;
#pragma unroll
        for (int j = 0; j < 8; ++j) dst[j] = fc[half + j];
      }
      __syncthreads();
      {
        float s = xpv;
#pragma unroll
        for (int p = 0; p < 8; ++p) s += red1[p * 544 + cR * 17 + bR];
        gs1[cR * 17 + bR] = s;
      }
      __syncthreads();
      if (tid < 128) {                     // cell update: (u_l = tid>>4, b = tid&15)
        int u_l = tid >> 4, b = tid & 15;
        int u = blk * 8 + u_l;
        float gi = gs1[(u_l * 4 + 0) * 17 + b];
        float gj = gs1[(u_l * 4 + 1) * 17 + b];
        float gf = gs1[(u_l * 4 + 2) * 17 + b];
        float go = gs1[(u_l * 4 + 3) * 17 + b];
        float cold = c1[b * 512 + u];      // block-private
        float cn = sigm(gf + 1.0f) * cold + sigm(gi) * tanh_(gj);
        float hn = sigm(go) * tanh_(cn);
        c1[b * 512 + u] = cn;
        cstore(h1n + b * 512 + u, hn);     // coherent publish
      }
      __syncthreads();                     // h1n stores ack'd at coherence point
      if (tid == 0) ustore(flag1 + blk, (unsigned)(t + 1));
      if (t < 63 && tid < 64) {
        unsigned tgt1 = (unsigned)(t + 1), tgt2 = (unsigned)t;
        for (;;) {
          bool ok = uload(flag1 + tid) >= tgt1;
          if (tid < 16) ok = ok && (uload(flag2 + tid) >= tgt2);
          if (__all(ok)) break;
          __builtin_amdgcn_s_sleep(1);
        }
      }
      __syncthreads();
    }
  } else {
    // ================= layer-2 blocks =================
    const int blk2 = blk - 64;             // 0..15
    float* stg2 = big;                     // [16][768] (overlaid by red after FMA)
    float* red  = big;                     // [8][64][17] = 8704 floats
    const int cB  = tid & 63, ks2 = tid >> 6;   // col 0..63, slice 0..7
    const int k0B = ks2 * 96;
    const int pB  = (cB & 3) * 256 + blk2 * 16 + (cB >> 2);
    const int colR = tid & 63, bq = tid >> 6;   // reduce role: 2 b's per thread
    const float blvR = bl2[(colR & 3) * 256 + blk2 * 16 + (colR >> 2)];
    float w2r[96];
#pragma unroll
    for (int i = 0; i < 96; ++i) w2r[i] = kl2[(size_t)(k0B + i) * 1024 + pB];

    for (int s = 0; s < 64; ++s) {
      const float* h1n = h1b + (size_t)((s + 1) & 1) * 8192;   // L1's step-s output
      const float* h2c = h2b + (size_t)(s & 1) * 4096;
      float* h2n       = h2b + (size_t)((s + 1) & 1) * 4096;

      if (tid < 64) {                      // start spin: inputs ready
        unsigned tgt1 = (unsigned)(s + 1), tgt2 = (unsigned)s;
        for (;;) {
          bool ok = uload(flag1 + tid) >= tgt1;
          if (tid < 16) ok = ok && (uload(flag2 + tid) >= tgt2);
          if (__all(ok)) break;
          __builtin_amdgcn_s_sleep(1);
        }
      }
      __syncthreads();

      // stage [h1n ; h2c] -> stg2[b*768 + k]
      float sw[24];
#pragma unroll
      for (int j = 0; j < 24; ++j) {
        int e = (j << 9) + tid;
        sw[j] = (j < 16) ? cload(h1n + e) : cload(h2c + (e - 8192));
      }
#pragma unroll
      for (int j = 0; j < 24; ++j) {
        if (j < 16) stg2[j * 768 + tid] = sw[j];
        else {
          int e = ((j - 16) << 9) + tid;
          stg2[(e >> 8) * 768 + 512 + (e & 255)] = sw[j];
        }
      }
      __syncthreads();

      float acc[16];
#pragma unroll
      for (int b = 0; b < 16; ++b) acc[b] = 0.f;
#pragma unroll
      for (int b = 0; b < 16; ++b) {
        const float* pb_ = stg2 + b * 768 + k0B;
#pragma unroll
        for (int sub = 0; sub < 4; ++sub) {
          float4 va[6];
#pragma unroll
          for (int i = 0; i < 6; ++i) va[i] = *(const float4*)(pb_ + sub * 24 + i * 4);
          const float* fa = (const float*)va;
#pragma unroll
          for (int j = 0; j < 24; ++j)
            acc[b] = fmaf(w2r[sub * 24 + j], fa[j], acc[b]);
        }
      }
      __syncthreads();                     // stg2 reads done; safe to overlay red
#pragma unroll
      for (int j = 0; j < 16; ++j) red[ks2 * 1088 + cB * 17 + j] = acc[j];
      __syncthreads();
      {
#pragma unroll
        for (int h = 0; h < 2; ++h) {
          int b = bq + h * 8;
          float sum = blvR;
#pragma unroll
          for (int w = 0; w < 8; ++w) sum += red[w * 1088 + colR * 17 + b];
          gs2[colR * 17 + b] = sum;
        }
      }
      __syncthreads();
      if (tid < 256) {                     // cell update: u = blk2*16 + (tid>>4)
        int u_l = tid >> 4, b = tid & 15;
        int u = blk2 * 16 + u_l;
        float gi = gs2[(u_l * 4 + 0) * 17 + b];
        float gj = gs2[(u_l * 4 + 1) * 17 + b];
        float gf = gs2[(u_l * 4 + 2) * 17 + b];
        float go = gs2[(u_l * 4 + 3) * 17 + b];
        float cold = c2[b * 256 + u];      // block-private
        float cn = sigm(gf + 1.0f) * cold + sigm(gi) * tanh_(gj);
        float hn = sigm(go) * tanh_(cn);
        c2[b * 256 + u] = cn;
        cstore(h2n + b * 256 + u, hn);     // coherent publish (peer L2 blocks read)
        out_seq[(size_t)((b << 6) + s) * 256 + u] = hn;  // normal; flushed at kernel end
      }
      __syncthreads();                     // h2n stores ack'd
      if (tid == 0) ustore(flag2 + blk2, (unsigned)(s + 1));
    }
  }
}

// ---- dense head: relu(lstm_out @ wd1 + bd1) @ wd2 + bd2 -> [1024] ----
__global__ void head_k(const float* __restrict__ xin, const float* __restrict__ wd1,
                       const float* __restrict__ bd1, const float* __restrict__ wd2,
                       const float* __restrict__ bd2, float* __restrict__ out) {
  __shared__ float xs[4][256];
  __shared__ float ps[4][128];
  int r0 = blockIdx.x * 4;
  int tid = threadIdx.x;
  for (int i = tid; i < 1024; i += 128) xs[i >> 8][i & 255] = xin[(size_t)r0 * 256 + i];
  __syncthreads();
  float w2 = wd2[tid];
  float bb = bd1[tid];
#pragma unroll
  for (int rr = 0; rr < 4; ++rr) {
    float acc = bb;
#pragma unroll 8
    for (int k = 0; k < 256; ++k) acc += xs[rr][k] * wd1[k * 128 + tid];
    ps[rr][tid] = fmaxf(acc, 0.0f) * w2;
  }
  __syncthreads();
  if (tid < 4) {
    float s = bd2[0];
    for (int k = 0; k < 128; ++k) s += ps[tid][k];
    out[r0 + tid] = s;
  }
}

extern "C" void kernel_launch(void* const* d_in, const int* in_sizes, int n_in,
                              void* d_out, int out_size, void* d_ws, size_t ws_size,
                              hipStream_t stream) {
  const float* frames  = (const float*)d_in[0];
  const float* actions = (const float*)d_in[1];
  const float* w1 = (const float*)d_in[2];   const float* b1 = (const float*)d_in[3];
  const float* w2 = (const float*)d_in[4];   const float* b2 = (const float*)d_in[5];
  const float* w3 = (const float*)d_in[6];   const float* b3 = (const float*)d_in[7];
  const float* w4 = (const float*)d_in[8];   const float* b4 = (const float*)d_in[9];
  const float* kl1 = (const float*)d_in[10]; const float* bl1 = (const float*)d_in[11];
  const float* kl2 = (const float*)d_in[12]; const float* bl2 = (const float*)d_in[13];
  const float* wd1 = (const float*)d_in[14]; const float* bd1 = (const float*)d_in[15];
  const float* wd2 = (const float*)d_in[16]; const float* bd2 = (const float*)d_in[17];
  float* out = (float*)d_out;

  float* ws = (float*)d_ws;
  float* a1    = ws;                 // [1024][31][31][32]
  float* a2    = ws + 31490048u;     // [1024][14][14][64]
  float* a3    = ws;                 // [1024][6][6][128]   (a1 dead)
  float* xin   = ws + 31490048u;     // [1024][1026]        (a2 dead)
  float* xpart = ws + 44335104u;     // [64][16][2048]
  float* h1b   = ws + 46432256u;     // [2][16][512]
  float* c1    = ws + 46448640u;     // [16][512]
  float* h2b   = ws + 46456832u;     // [2][16][256]
  float* c2    = ws + 46465024u;     // [16][256]
  unsigned* flg = (unsigned*)(ws + 46469120u);  // 512 words (flag1[64], flag2[16])
  float* lout  = ws + 46469632u;     // [16][64][256]

  hipMemsetAsync(h1b, 0, (36864 + 512) * sizeof(float), stream);

  conv1_k4<<<15872, 256, 0, stream>>>(frames, w1, b1, a1);
  conv_lds3<32, 64, 32, 31, 14><<<dim3(1568, 2), 512, 0, stream>>>(a1, w2, b2, a2, 14 * 14 * 64);
  conv_lds3<64, 128, 16, 14, 6><<<dim3(144, 8), 512, 0, stream>>>(a2, w3, b3, a3, 6 * 6 * 128);
  conv_lds3<128, 256, 8, 6, 2><<<dim3(8, 32), 512, 0, stream>>>(a3, w4, b4, xin, 1026);
  act_copy<<<8, 256, 0, stream>>>(actions, xin);
  gemm_xpart<<<dim3(32, 16), 256, 0, stream>>>(xin, kl1, bl1, xpart);

  void* args[10];
  args[0] = (void*)&xpart; args[1] = (void*)&kl1; args[2] = (void*)&kl2; args[3] = (void*)&bl2;
  args[4] = (void*)&h1b;   args[5] = (void*)&c1;  args[6] = (void*)&h2b; args[7] = (void*)&c2;
  args[8] = (void*)&flg;   args[9] = (void*)&lout;
  hipLaunchCooperativeKernel((void*)lstm_k, dim3(80), dim3(512), args, 0, stream);

  head_k<<<256, 128, 0, stream>>>(lout, wd1, bd1, wd2, bd2, out);
}